// Round 6
// baseline (595.194 us; speedup 1.0000x reference)
//
#include <hip/hip_runtime.h>
#include <hip/hip_bf16.h>

typedef __hip_bfloat16 bf16;
typedef float v4f __attribute__((ext_vector_type(4)));
typedef short v8s __attribute__((ext_vector_type(8)));

typedef const __attribute__((address_space(1))) void gvoid;
typedef __attribute__((address_space(3))) void lvoid;

__device__ __forceinline__ void async16(const void* g, void* l) {
  __builtin_amdgcn_global_load_lds((gvoid*)g, (lvoid*)l, 16, 0, 0);
}

__device__ __forceinline__ unsigned short f2bf(float v) {
  __hip_bfloat16 h = __float2bfloat16(v);
  return *(unsigned short*)&h;
}
__device__ __forceinline__ float bflo(unsigned dw) {
  unsigned u = dw << 16;
  return *(float*)&u;
}
__device__ __forceinline__ float bfhi(unsigned dw) {
  unsigned u = dw & 0xffff0000u;
  return *(float*)&u;
}

// cardinal cubic B-spline on [0,4], 0 outside. Reference bspline(t) == b3(4t),
// wavelet(t) == b3(8t) - b3(8t-4). Clamp makes u>=4 exactly 0 (64-108+48-4).
__device__ __forceinline__ float b3(float u) {
  u = fminf(fmaxf(u, 0.f), 4.f);
  float t1 = fmaxf(u - 1.f, 0.f);
  float t2 = fmaxf(u - 2.f, 0.f);
  float t3 = fmaxf(u - 3.f, 0.f);
  float c0 = u * u * u;
  float c1 = t1 * t1 * t1;
  float c2 = t2 * t2 * t2;
  float c3 = t3 * t3 * t3;
  return (c0 - 4.f * c1 + 6.f * c2 - 4.f * c3) * (1.f / 6.f);
}

// m97-style NT GEMM mainloop (used by gemm_proj): C[128 x NI*32] tile.
template <int NI, int BK>
__device__ __forceinline__ void mfma_loop(const bf16* __restrict__ A,
                                          const bf16* __restrict__ B, int lda,
                                          int ldb, int kLen, bf16* As, bf16* Bs,
                                          v4f acc[4][NI]) {
  const int tid = threadIdx.x;
  const int wave = tid >> 6;
  const int lane = tid & 63;
  const int quad = lane >> 4;
  const int r16 = lane & 15;
  const int wm = (wave >> 1) * 64;
  const int wn = (wave & 1) * (NI * 16);
  constexpr int CPR = BK / 8;          // 16B chunks per row
  constexpr int AQ = 128 * CPR / 256;  // async groups for A
  constexpr int BQ = NI * 32 * CPR / 256;
  char* AsC = (char*)As;
  char* BsC = (char*)Bs;
  for (int kk = 0; kk < kLen; kk += BK) {
#pragma unroll
    for (int q = 0; q < AQ; ++q) {
      const int ch = tid + 256 * q;
      const int r = ch / CPR, c = (ch % CPR) * 8;
      async16(A + (size_t)r * lda + kk + c, AsC + q * 4096 + wave * 1024);
    }
#pragma unroll
    for (int q = 0; q < BQ; ++q) {
      const int ch = tid + 256 * q;
      const int r = ch / CPR, c = (ch % CPR) * 8;
      async16(B + (size_t)r * ldb + kk + c, BsC + q * 4096 + wave * 1024);
    }
    __syncthreads();
#pragma unroll
    for (int ks = 0; ks < BK / 32; ++ks) {
      v8s af[4], bfr[NI];
#pragma unroll
      for (int mi = 0; mi < 4; ++mi)
        af[mi] =
            *(const v8s*)(As + (wm + mi * 16 + r16) * BK + ks * 32 + quad * 8);
#pragma unroll
      for (int ni = 0; ni < NI; ++ni)
        bfr[ni] =
            *(const v8s*)(Bs + (wn + ni * 16 + r16) * BK + ks * 32 + quad * 8);
#pragma unroll
      for (int mi = 0; mi < 4; ++mi)
#pragma unroll
        for (int ni = 0; ni < NI; ++ni)
          acc[mi][ni] = __builtin_amdgcn_mfma_f32_16x16x32_bf16(
              af[mi], bfr[ni], acc[mi][ni], 0, 0, 0);
    }
    __syncthreads();
  }
}

// per-row: sq-norm + bf16 cast of x into U[:, 0:256]
__global__ void prep(const float* __restrict__ x, bf16* __restrict__ U,
                     float* __restrict__ sq) {
  const int n = blockIdx.x, b = blockIdx.y, t = threadIdx.x;
  const size_t row = (size_t)b * 4096 + n;
  float v = x[row * 256 + t];
  U[row * 1280 + t] = __float2bfloat16(v);
  float s = v * v;
#pragma unroll
  for (int o = 32; o > 0; o >>= 1) s += __shfl_down(s, o, 64);
  __shared__ float ls[4];
  if ((t & 63) == 0) ls[t >> 6] = s;
  __syncthreads();
  if (t == 0) sq[row] = ls[0] + ls[1] + ls[2] + ls[3];
}

// fp32 [z][4096][256] -> bf16 [z][256][4096] (tiled transpose via LDS)
__global__ void transk(const float* __restrict__ src, bf16* __restrict__ dst) {
  __shared__ float tile[64][65];
  const int z = blockIdx.z;
  const float* s = src + (size_t)z * 4096 * 256;
  bf16* d = dst + (size_t)z * 256 * 4096;
  const int n0 = blockIdx.x * 64, d0 = blockIdx.y * 64;
  const int tx = threadIdx.x & 31, ty = threadIdx.x >> 5;
#pragma unroll
  for (int i = 0; i < 8; ++i) {
    const int r = ty + i * 8;
    const float2 v = *(const float2*)(s + (size_t)(n0 + r) * 256 + d0 + tx * 2);
    tile[r][tx * 2] = v.x;
    tile[r][tx * 2 + 1] = v.y;
  }
  __syncthreads();
#pragma unroll
  for (int i = 0; i < 8; ++i) {
    const int c = ty + i * 8;
    __hip_bfloat162 p;
    p.x = __float2bfloat16(tile[tx * 2][c]);
    p.y = __float2bfloat16(tile[tx * 2 + 1][c]);
    *(__hip_bfloat162*)(d + (size_t)(d0 + c) * 4096 + n0 + tx * 2) = p;
  }
}

// WbigT bf16 [128][1280]
__global__ void wbig(const float* __restrict__ Wk, const float* __restrict__ Wl,
                     bf16* __restrict__ WbT) {
  int idx = blockIdx.x * 256 + threadIdx.x;
  if (idx >= 128 * 1280) return;
  int j = idx / 1280, k = idx % 1280;
  int o = j & 63;
  float v = 0.f;
  if (k < 256)
    v = Wk[k * 64 + o] + Wl[k * 128 + j];
  else if (k < 512)
    v = (j < 64) ? Wk[16384 + (k - 256) * 64 + o] : 0.f;
  else if (k < 768)
    v = (j < 64) ? Wk[32768 + (k - 512) * 64 + o] : 0.f;
  else if (k < 1024)
    v = (j >= 64) ? Wk[16384 + (k - 768) * 64 + o] : 0.f;
  else
    v = (j >= 64) ? Wk[32768 + (k - 1024) * 64 + o] : 0.f;
  WbT[idx] = __float2bfloat16(v);
}

// Fused flash-style pass, v5 (spill fix). v4 structure was right (LDS 68K ->
// 2 blocks/CU, occupancy 21->43%) but __launch_bounds__(512,4) cornered the
// register allocator into the 64-VGPR arch config: VGPR_Count 64 + scratch
// spills (+120MB WRITE_SIZE, +27MB FETCH per dispatch vs the 32.8MB hpart
// floor) -- the same pathology the baseline's gemm_s comment documents for
// bounds>=3. Fix: bounds (512,2) (allocator free, like v3's spill-free 120
// VGPR). Persistent state ~80 regs (xi 32 + acc 32 + accs 16), peak ~115:
// fits <=128, so the HW still co-schedules 2 blocks/CU (LDS 2x68K<=160K,
// VGPR<=128 => 4 waves/SIMD) -- residency WITHOUT the forced reg cap.
// sqj preload moved into the epilogue to shave S-phase transient pressure.
// Numerics bit-identical to v4 (passed).
__global__ __launch_bounds__(512, 2) void fused_kh(
    const bf16* __restrict__ U, const float* __restrict__ sqv,
    const bf16* __restrict__ VB, int bstride, int vstride,
    bf16* __restrict__ hpart) {
  __shared__ __align__(16) bf16 Xj[2][128 * 32];  // pair-line swz8: 2x8K
  __shared__ __align__(16) bf16 Vt[2][256 * 32];  // pair-line swz8: 2x16K
  __shared__ __align__(16) bf16 P[64 * 128];      // swz8 rows 256B: 16K
  __shared__ unsigned short lut16[2048];          // 4K, this block's kernel

  const int tid = threadIdx.x;
  const int wave = tid >> 6, lane = tid & 63;
  const int quad = lane >> 4, r16 = lane & 15;
  const int par = lane & 1;
  const int wm = (wave >> 1) * 16;  // S i-rows (4 groups of 16)
  const int wns = (wave & 1) * 64;  // S j-cols (2 groups of 64)
  const int d0 = wave * 32;         // PV d-rows (8 groups of 32)
  const int i0 = blockIdx.x * 64;
  const int split = blockIdx.y;
  const int bk = blockIdx.z, b = bk >> 1, kern = bk & 1;

  for (int i = tid; i < 2048; i += 512) {
    float t = (i + 0.5f) * (1.f / 2048.f);
    float bv = b3(4.f * t);
    float wv = b3(8.f * t) - b3(8.f * t - 4.f);
    lut16[i] = kern ? f2bf(wv) : f2bf(bv);
  }

  const bf16* Vsrc = VB + (size_t)b * bstride + (size_t)kern * vstride;
  const bf16* Ub = U + (size_t)b * 4096 * 1280;

  // stage one K-chunk (32 cols) of Xj rows [j0g, j0g+128): pair-line layout,
  // line l holds rows {2l,2l+1}, slot s -> (row 2l+(c>>2), chunk c&3), c=s^(l&7)
  auto stageXj = [&](int buf, int j0g, int kq) {
    char* C = (char*)Xj[buf];
    const int line = tid >> 3, slot = tid & 7;
    const int c = slot ^ (line & 7);
    async16(Ub + (size_t)(j0g + line * 2 + (c >> 2)) * 1280 + kq * 32 +
                ((c & 3) << 3),
            C + wave * 1024);
  };
  // stage Vt[buf] = V^T[0:256][j0g + jc*32 ..+32), pair-line swz8
  auto stageVt = [&](int buf, int jc, int j0g) {
    char* C = (char*)Vt[buf];
#pragma unroll
    for (int q = 0; q < 2; ++q) {
      const int ch = tid + 512 * q;
      const int line = ch >> 3, slot = ch & 7;
      const int c = slot ^ (line & 7);
      async16(Vsrc + (size_t)(line * 2 + (c >> 2)) * 4096 + j0g + jc * 32 +
                  ((c & 3) << 3),
              C + q * 8192 + wave * 1024);
    }
  };

  // prologue: first Xj chunk + Xi fragment rows -> registers (one-time)
  stageXj(0, split * 1024, 0);
  v8s xi[8];  // A-fragments: row i0+wm+r16, k = kq*32 + quad*8
  {
    const bf16* src = Ub + (size_t)(i0 + wm + r16) * 1280 + quad * 8;
#pragma unroll
    for (int kq = 0; kq < 8; ++kq) xi[kq] = *(const v8s*)(src + kq * 32);
  }
  const float* sqr = sqv + b * 4096;
  float sqi[4];
#pragma unroll
  for (int r = 0; r < 4; ++r) sqi[r] = sqr[i0 + wm + quad * 4 + r];

  v4f acc[2][4];  // PV acc: h^T[d0 + mi*16][i0 + ni*16]
#pragma unroll
  for (int mi = 0; mi < 2; ++mi)
#pragma unroll
    for (int ni = 0; ni < 4; ++ni) acc[mi][ni] = (v4f){0.f, 0.f, 0.f, 0.f};

  const float cexp = -1.4426950408889634f / 512.f;  // -log2(e)/512
  __syncthreads();  // lut + Xj[0] ready

  for (int jt = 0; jt < 8; ++jt) {
    const int j0g = split * 1024 + jt * 128;

    // ---- S phase: accs = Xi(regs) @ Xj^T over 8 K-chunks, ping-pong ----
    v4f accs[4];
#pragma unroll
    for (int ni = 0; ni < 4; ++ni) accs[ni] = (v4f){0.f, 0.f, 0.f, 0.f};
#pragma unroll
    for (int kq = 0; kq < 8; ++kq) {
      if (kq < 7)
        stageXj((kq + 1) & 1, j0g, kq + 1);
      else
        stageVt(0, 0, j0g);  // first PV stage prefetch
      const bf16* Xq = Xj[kq & 1];
      __builtin_amdgcn_s_setprio(1);
      v8s bfr[4];
#pragma unroll
      for (int ni = 0; ni < 4; ++ni) {
        const int row = wns + ni * 16 + r16;
        const int line = row >> 1;
        const int sl = (((row & 1) << 2) + quad) ^ (line & 7);
        bfr[ni] = *(const v8s*)(Xq + line * 64 + sl * 8);
      }
#pragma unroll
      for (int ni = 0; ni < 4; ++ni)
        accs[ni] = __builtin_amdgcn_mfma_f32_16x16x32_bf16(xi[kq], bfr[ni],
                                                           accs[ni], 0, 0, 0);
      __builtin_amdgcn_s_setprio(0);
      __syncthreads();
    }
    // ---- spline epilogue: d2 -> LUT(kern) -> P into LDS (swizzled) ----
    float sqj[4];
#pragma unroll
    for (int ni = 0; ni < 4; ++ni) sqj[ni] = sqr[j0g + wns + ni * 16 + r16];
#pragma unroll
    for (int ni = 0; ni < 4; ++ni) {
      unsigned pv[4];
#pragma unroll
      for (int r = 0; r < 4; ++r) {
        float s = accs[ni][r];
        float d2 = fmaxf(sqi[r] + sqj[ni] - 2.f * s, 0.f);
        float t = __builtin_amdgcn_exp2f(d2 * cexp);
        int idx = (int)fminf(t * 2048.f, 2047.f);
        pv[r] = lut16[idx];
      }
      unsigned ov[4];
#pragma unroll
      for (int r = 0; r < 4; ++r) ov[r] = __shfl_xor((int)pv[r], 1, 64);
#pragma unroll
      for (int rr = 0; rr < 2; ++rr) {
        const int r = par * 2 + rr;
        const unsigned lo = par ? ov[r] : pv[r];  // even column value
        const unsigned hi = par ? pv[r] : ov[r];  // odd column value
        const int row = wm + quad * 4 + r;
        const int colp = wns + ni * 16 + (r16 & ~1);
        const int eoff =
            row * 128 + (((colp >> 3) ^ (row & 7)) << 3) + (colp & 7);
        *(unsigned*)(P + eoff) = (lo & 0xffffu) | (hi << 16);
      }
    }
    stageVt(1, 1, j0g);  // second PV stage, lands during epilogue drain
    __syncthreads();     // P visible; Vt[0] ready (staged during kq=7)
    // ---- PV phase: acc += Vt @ P^T, 4 j-chunks of 32, ping-pong Vt ----
#pragma unroll
    for (int jc = 0; jc < 4; ++jc) {
      if (jc == 1)
        stageVt(0, 2, j0g);
      else if (jc == 2)
        stageVt(1, 3, j0g);
      else if (jc == 3 && jt < 7)
        stageXj(0, j0g + 128, 0);  // next jt's first chunk
      const bf16* Vq = Vt[jc & 1];
      __builtin_amdgcn_s_setprio(1);
      v8s va[2], pb_[4];
#pragma unroll
      for (int mi = 0; mi < 2; ++mi) {
        const int d = d0 + mi * 16 + r16;
        const int line = d >> 1;
        const int sl = (((d & 1) << 2) + quad) ^ (line & 7);
        va[mi] = *(const v8s*)(Vq + line * 64 + sl * 8);
      }
#pragma unroll
      for (int ni = 0; ni < 4; ++ni) {
        const int row = ni * 16 + r16;
        const int ck = jc * 4 + quad;
        pb_[ni] = *(const v8s*)(P + row * 128 + ((ck ^ (row & 7)) << 3));
      }
#pragma unroll
      for (int mi = 0; mi < 2; ++mi)
#pragma unroll
        for (int ni = 0; ni < 4; ++ni)
          acc[mi][ni] = __builtin_amdgcn_mfma_f32_16x16x32_bf16(
              va[mi], pb_[ni], acc[mi][ni], 0, 0, 0);
      __builtin_amdgcn_s_setprio(0);
      __syncthreads();
    }
  }
  // ---- write bf16 partials: H[d][i], packed i-pairs, dword stores ----
  bf16* H = hpart + ((size_t)split * 4 + bk) * 4096 * 256;
#pragma unroll
  for (int mi = 0; mi < 2; ++mi) {
#pragma unroll
    for (int ni = 0; ni < 4; ++ni) {
      unsigned pv[4];
#pragma unroll
      for (int r = 0; r < 4; ++r) pv[r] = (unsigned)f2bf(acc[mi][ni][r]);
      unsigned ov[4];
#pragma unroll
      for (int r = 0; r < 4; ++r) ov[r] = __shfl_xor((int)pv[r], 1, 64);
#pragma unroll
      for (int rr = 0; rr < 2; ++rr) {
        const int r = par * 2 + rr;
        const unsigned ea = pv[r], eb = ov[r];
        const unsigned lo = par ? eb : ea;
        const unsigned hi = par ? ea : eb;
        const int d = d0 + mi * 16 + quad * 4 + r;
        const int ic = i0 + ni * 16 + (r16 & ~1);
        *(unsigned*)(H + (size_t)d * 4096 + ic) = lo | (hi << 16);
      }
    }
  }
}

// sum the four bf16 split-K partials ([256 d][4096 n] slabs); write bf16
// slice into U[:, uoff..] (transposing via LDS) and (pass 1 only) direct
// bf16 copy into hT [z][256][4096].
__global__ void reduceT(const bf16* __restrict__ hpart, bf16* __restrict__ U,
                        bf16* __restrict__ hT, int uoffBase) {
  __shared__ float tile[64][65];  // [d-local][n-local]
  const int z = blockIdx.z;
  const int b = z >> 1, kern = z & 1;
  const int uoff = uoffBase + kern * 512;
  const int n0 = blockIdx.x * 64, d0 = blockIdx.y * 64;
  const int tx = threadIdx.x & 31, ty = threadIdx.x >> 5;
  const size_t sstride = (size_t)4 * 4096 * 256;
  const bf16* s0 = hpart + (size_t)z * 4096 * 256;
#pragma unroll
  for (int i = 0; i < 8; ++i) {
    const int dl = ty + i * 8;
    const size_t off = (size_t)(d0 + dl) * 4096 + n0 + tx * 2;
    float vx = 0.f, vy = 0.f;
#pragma unroll
    for (int k = 0; k < 4; ++k) {
      const unsigned dw = *(const unsigned*)(s0 + k * sstride + off);
      vx += bflo(dw);
      vy += bfhi(dw);
    }
    tile[dl][tx * 2] = vx;
    tile[dl][tx * 2 + 1] = vy;
    if (hT) {
      __hip_bfloat162 p;
      p.x = __float2bfloat16(vx);
      p.y = __float2bfloat16(vy);
      *(__hip_bfloat162*)(hT + (size_t)z * 256 * 4096 + off) = p;
    }
  }
  __syncthreads();
#pragma unroll
  for (int i = 0; i < 8; ++i) {
    const int c = ty + i * 8;  // n-local
    __hip_bfloat162 p;
    p.x = __float2bfloat16(tile[tx * 2][c]);
    p.y = __float2bfloat16(tile[tx * 2 + 1][c]);
    *(__hip_bfloat162*)(U + (size_t)(b * 4096 + n0 + c) * 1280 + uoff + d0 +
                        tx * 2) = p;
  }
}

// out = relu(U @ Wbig + b_lin), M=8192, K=1280, N=128
__global__ __launch_bounds__(256, 4) void gemm_proj(
    const bf16* __restrict__ U, const bf16* __restrict__ WbT,
    const float* __restrict__ blin, float* __restrict__ out) {
  __shared__ __align__(16) bf16 As[128 * 64];
  __shared__ __align__(16) bf16 Bs[64 * 64];
  const bf16* A = U + (size_t)blockIdx.x * 128 * 1280;
  const bf16* B = WbT + (size_t)blockIdx.y * 64 * 1280;
  v4f acc[4][2];
#pragma unroll
  for (int a = 0; a < 4; ++a)
#pragma unroll
    for (int b2 = 0; b2 < 2; ++b2) acc[a][b2] = (v4f){0.f, 0.f, 0.f, 0.f};
  mfma_loop<2, 64>(A, B, 1280, 1280, 1280, As, Bs, acc);
  const int tid = threadIdx.x, wave = tid >> 6, lane = tid & 63;
  const int quad = lane >> 4, r16 = lane & 15;
  const int wm = (wave >> 1) * 64, wn = (wave & 1) * 32;
  const int i0 = blockIdx.x * 128 + wm + quad * 4;
  const int j0 = blockIdx.y * 64 + wn + r16;
#pragma unroll
  for (int mi = 0; mi < 4; ++mi)
#pragma unroll
    for (int r = 0; r < 4; ++r) {
      const int i = i0 + mi * 16 + r;
#pragma unroll
      for (int ni = 0; ni < 2; ++ni) {
        const int j = j0 + ni * 16;
        out[(size_t)i * 128 + j] = fmaxf(acc[mi][ni][r] + blin[j], 0.f);
      }
    }
}

extern "C" void kernel_launch(void* const* d_in, const int* in_sizes, int n_in,
                              void* d_out, int out_size, void* d_ws,
                              size_t ws_size, hipStream_t stream) {
  const float* x = (const float*)d_in[0];
  const float* Wk = (const float*)d_in[1];
  const float* Wlin = (const float*)d_in[2];
  const float* blin = (const float*)d_in[3];
  float* out = (float*)d_out;
  char* w = (char*)d_ws;
  // workspace layout (bytes):
  bf16* hpart = (bf16*)(w);               // 4*4*256*4096*2    = 33554432
  bf16* h1T = (bf16*)(w + 33554432);      // 4 * 256*4096 * 2  = 8388608
  bf16* xhT = (bf16*)(w + 41943040);      // 2 * 256*4096 * 2  = 4194304
  bf16* U = (bf16*)(w + 46137344);        // 8192*1280 * 2     = 20971520
  bf16* WbT = (bf16*)(w + 67108864);      // 128*1280 * 2      = 327680
  float* sqv = (float*)(w + 67436544);    // 8192 * 4          = 32768
  // total ~67.5 MB

  prep<<<dim3(4096, 2), 256, 0, stream>>>(x, U, sqv);
  transk<<<dim3(64, 4, 2), 256, 0, stream>>>(x, xhT);
  wbig<<<dim3(640), 256, 0, stream>>>(Wk, Wlin, WbT);
  // pass 1: h1 = spline(x x^T) @ x   (V = xhT[b], both kernels same plane)
  fused_kh<<<dim3(64, 4, 4), 512, 0, stream>>>(U, sqv, xhT, 256 * 4096, 0,
                                               hpart);
  reduceT<<<dim3(64, 4, 4), 256, 0, stream>>>(hpart, U, h1T, 256);
  // pass 2: h2 = spline(x x^T) @ h1  (V = h1T plane (b,kern))
  fused_kh<<<dim3(64, 4, 4), 512, 0, stream>>>(U, sqv, h1T, 2 * 256 * 4096,
                                               256 * 4096, hpart);
  reduceT<<<dim3(64, 4, 4), 256, 0, stream>>>(hpart, U, nullptr, 512);
  gemm_proj<<<dim3(64, 2), 256, 0, stream>>>(U, WbT, blin, out);
}

// Round 7
// 412.619 us; speedup vs baseline: 1.4425x; 1.4425x over previous
//
#include <hip/hip_runtime.h>
#include <hip/hip_bf16.h>

typedef __hip_bfloat16 bf16;
typedef float v4f __attribute__((ext_vector_type(4)));
typedef short v8s __attribute__((ext_vector_type(8)));

typedef const __attribute__((address_space(1))) void gvoid;
typedef __attribute__((address_space(3))) void lvoid;

__device__ __forceinline__ void async16(const void* g, void* l) {
  __builtin_amdgcn_global_load_lds((gvoid*)g, (lvoid*)l, 16, 0, 0);
}

// counted gate: wait until <=M vector-mem ops outstanding, then raw barrier.
// NEVER vmcnt(0) in steady state -- prefetches stay in flight across barriers
// (T3/T4 mechanism; __syncthreads would drain everything = v3's 100us stall).
// sched_barrier(0) stops hipcc hoisting LDS reads above the gate (rule #18).
#define GATE(M)                                             \
  do {                                                      \
    asm volatile("s_waitcnt vmcnt(" #M ")" ::: "memory");   \
    __builtin_amdgcn_s_barrier();                           \
    __builtin_amdgcn_sched_barrier(0);                      \
  } while (0)

__device__ __forceinline__ unsigned short f2bf(float v) {
  __hip_bfloat16 h = __float2bfloat16(v);
  return *(unsigned short*)&h;
}
__device__ __forceinline__ float bflo(unsigned dw) {
  unsigned u = dw << 16;
  return *(float*)&u;
}
__device__ __forceinline__ float bfhi(unsigned dw) {
  unsigned u = dw & 0xffff0000u;
  return *(float*)&u;
}

// cardinal cubic B-spline on [0,4], 0 outside. Reference bspline(t) == b3(4t),
// wavelet(t) == b3(8t) - b3(8t-4). Clamp makes u>=4 exactly 0 (64-108+48-4).
__device__ __forceinline__ float b3(float u) {
  u = fminf(fmaxf(u, 0.f), 4.f);
  float t1 = fmaxf(u - 1.f, 0.f);
  float t2 = fmaxf(u - 2.f, 0.f);
  float t3 = fmaxf(u - 3.f, 0.f);
  float c0 = u * u * u;
  float c1 = t1 * t1 * t1;
  float c2 = t2 * t2 * t2;
  float c3 = t3 * t3 * t3;
  return (c0 - 4.f * c1 + 6.f * c2 - 4.f * c3) * (1.f / 6.f);
}

// m97-style NT GEMM mainloop (used by gemm_proj): C[128 x NI*32] tile.
template <int NI, int BK>
__device__ __forceinline__ void mfma_loop(const bf16* __restrict__ A,
                                          const bf16* __restrict__ B, int lda,
                                          int ldb, int kLen, bf16* As, bf16* Bs,
                                          v4f acc[4][NI]) {
  const int tid = threadIdx.x;
  const int wave = tid >> 6;
  const int lane = tid & 63;
  const int quad = lane >> 4;
  const int r16 = lane & 15;
  const int wm = (wave >> 1) * 64;
  const int wn = (wave & 1) * (NI * 16);
  constexpr int CPR = BK / 8;          // 16B chunks per row
  constexpr int AQ = 128 * CPR / 256;  // async groups for A
  constexpr int BQ = NI * 32 * CPR / 256;
  char* AsC = (char*)As;
  char* BsC = (char*)Bs;
  for (int kk = 0; kk < kLen; kk += BK) {
#pragma unroll
    for (int q = 0; q < AQ; ++q) {
      const int ch = tid + 256 * q;
      const int r = ch / CPR, c = (ch % CPR) * 8;
      async16(A + (size_t)r * lda + kk + c, AsC + q * 4096 + wave * 1024);
    }
#pragma unroll
    for (int q = 0; q < BQ; ++q) {
      const int ch = tid + 256 * q;
      const int r = ch / CPR, c = (ch % CPR) * 8;
      async16(B + (size_t)r * ldb + kk + c, BsC + q * 4096 + wave * 1024);
    }
    __syncthreads();
#pragma unroll
    for (int ks = 0; ks < BK / 32; ++ks) {
      v8s af[4], bfr[NI];
#pragma unroll
      for (int mi = 0; mi < 4; ++mi)
        af[mi] =
            *(const v8s*)(As + (wm + mi * 16 + r16) * BK + ks * 32 + quad * 8);
#pragma unroll
      for (int ni = 0; ni < NI; ++ni)
        bfr[ni] =
            *(const v8s*)(Bs + (wn + ni * 16 + r16) * BK + ks * 32 + quad * 8);
#pragma unroll
      for (int mi = 0; mi < 4; ++mi)
#pragma unroll
        for (int ni = 0; ni < NI; ++ni)
          acc[mi][ni] = __builtin_amdgcn_mfma_f32_16x16x32_bf16(
              af[mi], bfr[ni], acc[mi][ni], 0, 0, 0);
    }
    __syncthreads();
  }
}

// per-row: sq-norm + bf16 cast of x into U[:, 0:256]
__global__ void prep(const float* __restrict__ x, bf16* __restrict__ U,
                     float* __restrict__ sq) {
  const int n = blockIdx.x, b = blockIdx.y, t = threadIdx.x;
  const size_t row = (size_t)b * 4096 + n;
  float v = x[row * 256 + t];
  U[row * 1280 + t] = __float2bfloat16(v);
  float s = v * v;
#pragma unroll
  for (int o = 32; o > 0; o >>= 1) s += __shfl_down(s, o, 64);
  __shared__ float ls[4];
  if ((t & 63) == 0) ls[t >> 6] = s;
  __syncthreads();
  if (t == 0) sq[row] = ls[0] + ls[1] + ls[2] + ls[3];
}

// fp32 [z][4096][256] -> bf16 [z][256][4096] (tiled transpose via LDS)
__global__ void transk(const float* __restrict__ src, bf16* __restrict__ dst) {
  __shared__ float tile[64][65];
  const int z = blockIdx.z;
  const float* s = src + (size_t)z * 4096 * 256;
  bf16* d = dst + (size_t)z * 256 * 4096;
  const int n0 = blockIdx.x * 64, d0 = blockIdx.y * 64;
  const int tx = threadIdx.x & 31, ty = threadIdx.x >> 5;
#pragma unroll
  for (int i = 0; i < 8; ++i) {
    const int r = ty + i * 8;
    const float2 v = *(const float2*)(s + (size_t)(n0 + r) * 256 + d0 + tx * 2);
    tile[r][tx * 2] = v.x;
    tile[r][tx * 2 + 1] = v.y;
  }
  __syncthreads();
#pragma unroll
  for (int i = 0; i < 8; ++i) {
    const int c = ty + i * 8;
    __hip_bfloat162 p;
    p.x = __float2bfloat16(tile[tx * 2][c]);
    p.y = __float2bfloat16(tile[tx * 2 + 1][c]);
    *(__hip_bfloat162*)(d + (size_t)(d0 + c) * 4096 + n0 + tx * 2) = p;
  }
}

// WbigT bf16 [128][1280]
__global__ void wbig(const float* __restrict__ Wk, const float* __restrict__ Wl,
                     bf16* __restrict__ WbT) {
  int idx = blockIdx.x * 256 + threadIdx.x;
  if (idx >= 128 * 1280) return;
  int j = idx / 1280, k = idx % 1280;
  int o = j & 63;
  float v = 0.f;
  if (k < 256)
    v = Wk[k * 64 + o] + Wl[k * 128 + j];
  else if (k < 512)
    v = (j < 64) ? Wk[16384 + (k - 256) * 64 + o] : 0.f;
  else if (k < 768)
    v = (j < 64) ? Wk[32768 + (k - 512) * 64 + o] : 0.f;
  else if (k < 1024)
    v = (j >= 64) ? Wk[16384 + (k - 768) * 64 + o] : 0.f;
  else
    v = (j >= 64) ? Wk[32768 + (k - 1024) * 64 + o] : 0.f;
  WbT[idx] = __float2bfloat16(v);
}

// Fused flash-style pass, v6 = v3 geometry + counted-vmcnt pipeline.
// v3 (best fused: 126us, VGPR 120 no-spill) lost ~100us/dispatch to the
// vmcnt(0) drain inside each of 9 __syncthreads/jt at 1 block/CU. v6 keeps
// v3's compute/layout code verbatim but replaces every barrier with
// GATE(M): counted s_waitcnt vmcnt(M) + raw s_barrier, so prefetched
// global_load_lds ops stay in flight ACROSS barriers (T3/T4; m201 template).
// Stage rings: Xj ring-3 (16K chunks, issued 2+ slots ahead), Vt ring-4
// single-plane chunks (PV does kern 0,1 sequentially per j-chunk;
// acc[2][2][4]); sqj preloaded to LDS so no compiler global loads pollute
// the vmcnt window. Slot schedule per jt (issue at top, gate at end):
//   S0:+X2  g2 | S1:+X3 g2 | S2:+V(*,0) g4 | S3:+V(*,1) (no gate) |
//   E  lgkm0+g4 | P0:+X0' g2 (jt=7: g0) | P1:+V(*,2) g0 | P2:+V(*,3) g0 |
//   P3:+X1' g10
// Counts proven by in-order vmcnt retirement; buffer reuse separated by >=1
// barrier at every issue point. Numerics bit-identical to v3 (same MFMA
// shapes, same K/jc order, same LUT + epilogue math).
// LDS: Xj 3x16K + Vt 4x16K + Pb/Pw 32K + lut 8K + sqjL 4K = 156K.
__global__ __launch_bounds__(512, 2) void fused_kh(
    const bf16* __restrict__ U, const float* __restrict__ sqv,
    const bf16* __restrict__ VbB, const bf16* __restrict__ VwB, int bstrideV,
    bf16* __restrict__ hpart) {
  __shared__ __align__(16) bf16 XjL[3][128 * 64];  // swz8 rows 128B
  __shared__ __align__(16) bf16 VtL[4][256 * 32];  // pair-line swz8
  __shared__ __align__(16) bf16 Pb[64 * 128];      // swz8 rows 256B
  __shared__ __align__(16) bf16 Pw[64 * 128];
  __shared__ unsigned lut[2048];
  __shared__ float sqjL[1024];

  const int tid = threadIdx.x;
  const int wave = tid >> 6, lane = tid & 63;
  const int quad = lane >> 4, r16 = lane & 15;
  const int par = lane & 1;
  const int grp = wave >> 2;        // S i-group
  const int wm = grp * 32;          // S i-rows (2 groups of 32)
  const int wns = (wave & 3) * 32;  // S j-cols (4 groups of 32)
  const int d0 = wave * 32;         // PV d-rows (8 groups of 32)
  const int i0 = blockIdx.x * 64;
  const int split = blockIdx.y;
  const int b = blockIdx.z;

  for (int i = tid; i < 2048; i += 512) {
    float t = (i + 0.5f) * (1.f / 2048.f);
    float bv = b3(4.f * t);
    float wv = b3(8.f * t) - b3(8.f * t - 4.f);
    lut[i] = (unsigned)f2bf(bv) | ((unsigned)f2bf(wv) << 16);
  }

  const bf16* Vb = VbB + (size_t)b * bstrideV;
  const bf16* Vw = VwB + (size_t)b * bstrideV;
  const bf16* Ub = U + (size_t)b * 4096 * 1280;
  const float* sqr = sqv + b * 4096;

  // stage one K-chunk (64 cols) of Xj rows [j0g, j0g+128) into Cb (swz8)
  auto stageX = [&](bf16* Cb, int j0g, int kq) {
    char* C = (char*)Cb;
#pragma unroll
    for (int q = 0; q < 2; ++q) {
      const int ch = tid + 512 * q;
      const int r = ch >> 3, cp = ch & 7;
      async16(Ub + (size_t)(j0g + r) * 1280 + kq * 64 + ((cp ^ (r & 7)) << 3),
              C + q * 8192 + wave * 1024);
    }
  };
  // stage Vt chunk = Vp^T[0:256][j0g + jc*32 ..+32), pair-line swz8
  auto stageV = [&](bf16* Cb, const bf16* Vp, int j0g, int jc) {
    char* C = (char*)Cb;
#pragma unroll
    for (int q = 0; q < 2; ++q) {
      const int ch = tid + 512 * q;
      const int line = ch >> 3, slot = ch & 7;
      const int c = slot ^ (line & 7);
      async16(Vp + (size_t)(line * 2 + (c >> 2)) * 4096 + j0g + jc * 32 +
                  ((c & 3) << 3),
              C + q * 8192 + wave * 1024);
    }
  };

  bf16* xq0 = XjL[0];
  bf16* xq1 = XjL[1];
  bf16* xq2 = XjL[2];

  // ---- prologue: sqjL + X0,X1 staged; Xi + sqi -> regs; one full drain ----
  if (wave < 4)
    async16((const char*)(sqr + split * 1024) + tid * 16,
            (char*)sqjL + wave * 1024);
  stageX(xq0, split * 1024, 0);
  stageX(xq1, split * 1024, 1);

  v8s xi[2][8];  // Xi[wm + mi*16 + r16][k = kq*64 + ks*32 + quad*8 ..+8]
  {
    const bf16* src = Ub + (size_t)(i0 + wm) * 1280;
#pragma unroll
    for (int mi = 0; mi < 2; ++mi)
#pragma unroll
      for (int ck = 0; ck < 8; ++ck)
        xi[mi][ck] = *(const v8s*)(src + (size_t)(mi * 16 + r16) * 1280 +
                                   ((ck >> 1) * 8 + (ck & 1) * 4 + quad) * 8);
  }
  float sqi[8];
#pragma unroll
  for (int mi = 0; mi < 2; ++mi)
#pragma unroll
    for (int r = 0; r < 4; ++r)
      sqi[mi * 4 + r] = sqr[i0 + wm + mi * 16 + quad * 4 + r];

  v4f acc[2][2][4];  // [kern][mi: d 2x16][ni: i 4x16]
#pragma unroll
  for (int k = 0; k < 2; ++k)
#pragma unroll
    for (int mi = 0; mi < 2; ++mi)
#pragma unroll
      for (int ni = 0; ni < 4; ++ni) acc[k][mi][ni] = (v4f){0.f, 0.f, 0.f, 0.f};

  const float cexp = -1.4426950408889634f / 512.f;  // -log2(e)/512

  asm volatile("s_waitcnt vmcnt(0) lgkmcnt(0)" ::: "memory");
  __builtin_amdgcn_s_barrier();
  __builtin_amdgcn_sched_barrier(0);

// S sub-phase: 8 MFMA from xi regs + Xq chunk KQ (literal!)
#define S_BODY(XQ, KQ)                                                      \
  {                                                                         \
    __builtin_amdgcn_s_setprio(1);                                          \
    _Pragma("unroll") for (int ks = 0; ks < 2; ++ks) {                      \
      v8s bfr[2];                                                           \
      _Pragma("unroll") for (int ni = 0; ni < 2; ++ni) {                    \
        const int row = wns + ni * 16 + r16;                                \
        const int ck = ks * 4 + quad;                                       \
        bfr[ni] = *(const v8s*)((XQ) + row * 64 + ((ck ^ (row & 7)) << 3)); \
      }                                                                     \
      _Pragma("unroll") for (int mi = 0; mi < 2; ++mi)                      \
          _Pragma("unroll") for (int ni = 0; ni < 2; ++ni) accs[mi][ni] =   \
          __builtin_amdgcn_mfma_f32_16x16x32_bf16(                          \
              xi[mi][(KQ)*2 + ks], bfr[ni], accs[mi][ni], 0, 0, 0);         \
    }                                                                       \
    __builtin_amdgcn_s_setprio(0);                                          \
  }

// PV sub-phase for j-chunk JC (literal): kern 0,1 sequential, 16 MFMA
#define PV_BODY(JC)                                                          \
  {                                                                          \
    __builtin_amdgcn_s_setprio(1);                                           \
    _Pragma("unroll") for (int k = 0; k < 2; ++k) {                          \
      const bf16* Vq = VtL[(2 * (JC) + k) & 3];                              \
      const bf16* Pk = k ? Pw : Pb;                                          \
      v8s va[2], pb_[4];                                                     \
      _Pragma("unroll") for (int mi = 0; mi < 2; ++mi) {                     \
        const int d = d0 + mi * 16 + r16;                                    \
        const int line = d >> 1;                                             \
        const int sl = (((d & 1) << 2) + quad) ^ (line & 7);                 \
        va[mi] = *(const v8s*)(Vq + line * 64 + sl * 8);                     \
      }                                                                      \
      _Pragma("unroll") for (int ni = 0; ni < 4; ++ni) {                     \
        const int row = ni * 16 + r16;                                       \
        const int ck = (JC)*4 + quad;                                        \
        pb_[ni] = *(const v8s*)(Pk + row * 128 + ((ck ^ (row & 7)) << 3));   \
      }                                                                      \
      _Pragma("unroll") for (int mi = 0; mi < 2; ++mi)                       \
          _Pragma("unroll") for (int ni = 0; ni < 4; ++ni) acc[k][mi][ni] =  \
          __builtin_amdgcn_mfma_f32_16x16x32_bf16(va[mi], pb_[ni],           \
                                                  acc[k][mi][ni], 0, 0, 0);  \
    }                                                                        \
    __builtin_amdgcn_s_setprio(0);                                           \
  }

  for (int jt = 0; jt < 8; ++jt) {
    const int j0g = split * 1024 + jt * 128;
    v4f accs[2][2];
#pragma unroll
    for (int mi = 0; mi < 2; ++mi)
#pragma unroll
      for (int ni = 0; ni < 2; ++ni) accs[mi][ni] = (v4f){0.f, 0.f, 0.f, 0.f};

    // ---- S0 ----
    stageX(xq2, j0g, 2);
    S_BODY(xq0, 0);
    GATE(2);
    // ---- S1 ----
    stageX(xq0, j0g, 3);  // X3 reuses xq0 (X0 consumed in S0, barrier since)
    S_BODY(xq1, 1);
    GATE(2);
    // ---- S2 ----
    stageV(VtL[0], Vb, j0g, 0);
    stageV(VtL[1], Vw, j0g, 0);
    S_BODY(xq2, 2);
    GATE(4);
    // ---- S3 (no gate: epilogue uses regs only; P-readers are 4+ barriers
    // back) ----
    stageV(VtL[2], Vb, j0g, 1);
    stageV(VtL[3], Vw, j0g, 1);
    S_BODY(xq0, 3);
    // ---- E: spline epilogue -> Pb/Pw (swizzled paired dwords) ----
    {
      float sqj[2];
#pragma unroll
      for (int ni = 0; ni < 2; ++ni)
        sqj[ni] = sqjL[jt * 128 + wns + ni * 16 + r16];
#pragma unroll
      for (int mi = 0; mi < 2; ++mi) {
#pragma unroll
        for (int ni = 0; ni < 2; ++ni) {
          unsigned pv[4];
#pragma unroll
          for (int r = 0; r < 4; ++r) {
            float s = accs[mi][ni][r];
            float d2 = fmaxf(sqi[mi * 4 + r] + sqj[ni] - 2.f * s, 0.f);
            float t = __builtin_amdgcn_exp2f(d2 * cexp);
            int idx = (int)fminf(t * 2048.f, 2047.f);
            pv[r] = lut[idx];
          }
          unsigned ov[4];
#pragma unroll
          for (int r = 0; r < 4; ++r) ov[r] = __shfl_xor((int)pv[r], 1, 64);
#pragma unroll
          for (int rr = 0; rr < 2; ++rr) {
            const int r = par * 2 + rr;
            const unsigned ea = pv[r], eb = ov[r];
            const unsigned lo = par ? eb : ea;  // even column
            const unsigned hi = par ? ea : eb;  // odd column
            const int row = wm + mi * 16 + quad * 4 + r;
            const int colp = wns + ni * 16 + (r16 & ~1);
            const int eoff =
                row * 128 + (((colp >> 3) ^ (row & 7)) << 3) + (colp & 7);
            *(unsigned*)(Pb + eoff) = (lo & 0xffffu) | (hi << 16);
            *(unsigned*)(Pw + eoff) = (lo >> 16) | (hi & 0xffff0000u);
          }
        }
      }
    }
    asm volatile("s_waitcnt lgkmcnt(0)" ::: "memory");  // flush P ds_writes
    GATE(4);
    // ---- P0 ----
    if (jt < 7) {
      stageX(xq1, j0g + 128, 0);  // next jt's X0 (xq1 free since S1)
      PV_BODY(0);
      GATE(2);
    } else {
      PV_BODY(0);
      GATE(0);  // no X0' issued: must fully retire V(*,1) here
    }
    // ---- P1 ----
    stageV(VtL[0], Vb, j0g, 2);
    stageV(VtL[1], Vw, j0g, 2);
    PV_BODY(1);
    GATE(0);
    // ---- P2 ----
    stageV(VtL[2], Vb, j0g, 3);
    stageV(VtL[3], Vw, j0g, 3);
    PV_BODY(2);
    GATE(0);
    // ---- P3 ----
    if (jt < 7) stageX(xq2, j0g + 128, 1);  // next jt's X1 (xq2 free since S2)
    PV_BODY(3);
    GATE(10);
    // rotate X ring: next jt sees X0 in xq0, X1 in xq1
    bf16* t = xq0;
    xq0 = xq1;
    xq1 = xq2;
    xq2 = t;
  }
#undef S_BODY
#undef PV_BODY

  // ---- write bf16 partials: H[d][i] slabs, packed i-pairs, dword stores ----
#pragma unroll
  for (int kern = 0; kern < 2; ++kern) {
    bf16* H = hpart + ((size_t)split * 4 + b * 2 + kern) * 4096 * 256;
#pragma unroll
    for (int mi = 0; mi < 2; ++mi) {
#pragma unroll
      for (int ni = 0; ni < 4; ++ni) {
        unsigned pv[4];
#pragma unroll
        for (int r = 0; r < 4; ++r) pv[r] = (unsigned)f2bf(acc[kern][mi][ni][r]);
        unsigned ov[4];
#pragma unroll
        for (int r = 0; r < 4; ++r) ov[r] = __shfl_xor((int)pv[r], 1, 64);
#pragma unroll
        for (int rr = 0; rr < 2; ++rr) {
          const int r = par * 2 + rr;
          const unsigned ea = pv[r], eb = ov[r];
          const unsigned lo = par ? eb : ea;
          const unsigned hi = par ? ea : eb;
          const int d = d0 + mi * 16 + quad * 4 + r;
          const int ic = i0 + ni * 16 + (r16 & ~1);
          *(unsigned*)(H + (size_t)d * 4096 + ic) = lo | (hi << 16);
        }
      }
    }
  }
}

// sum the four bf16 split-K partials ([256 d][4096 n] slabs); write bf16
// slice into U[:, uoff..] (transposing via LDS) and (pass 1 only) direct
// bf16 copy into hT [z][256][4096].
__global__ void reduceT(const bf16* __restrict__ hpart, bf16* __restrict__ U,
                        bf16* __restrict__ hT, int uoffBase) {
  __shared__ float tile[64][65];  // [d-local][n-local]
  const int z = blockIdx.z;
  const int b = z >> 1, kern = z & 1;
  const int uoff = uoffBase + kern * 512;
  const int n0 = blockIdx.x * 64, d0 = blockIdx.y * 64;
  const int tx = threadIdx.x & 31, ty = threadIdx.x >> 5;
  const size_t sstride = (size_t)4 * 4096 * 256;
  const bf16* s0 = hpart + (size_t)z * 4096 * 256;
#pragma unroll
  for (int i = 0; i < 8; ++i) {
    const int dl = ty + i * 8;
    const size_t off = (size_t)(d0 + dl) * 4096 + n0 + tx * 2;
    float vx = 0.f, vy = 0.f;
#pragma unroll
    for (int k = 0; k < 4; ++k) {
      const unsigned dw = *(const unsigned*)(s0 + k * sstride + off);
      vx += bflo(dw);
      vy += bfhi(dw);
    }
    tile[dl][tx * 2] = vx;
    tile[dl][tx * 2 + 1] = vy;
    if (hT) {
      __hip_bfloat162 p;
      p.x = __float2bfloat16(vx);
      p.y = __float2bfloat16(vy);
      *(__hip_bfloat162*)(hT + (size_t)z * 256 * 4096 + off) = p;
    }
  }
  __syncthreads();
#pragma unroll
  for (int i = 0; i < 8; ++i) {
    const int c = ty + i * 8;  // n-local
    __hip_bfloat162 p;
    p.x = __float2bfloat16(tile[tx * 2][c]);
    p.y = __float2bfloat16(tile[tx * 2 + 1][c]);
    *(__hip_bfloat162*)(U + (size_t)(b * 4096 + n0 + c) * 1280 + uoff + d0 +
                        tx * 2) = p;
  }
}

// out = relu(U @ Wbig + b_lin), M=8192, K=1280, N=128
__global__ __launch_bounds__(256, 4) void gemm_proj(
    const bf16* __restrict__ U, const bf16* __restrict__ WbT,
    const float* __restrict__ blin, float* __restrict__ out) {
  __shared__ __align__(16) bf16 As[128 * 64];
  __shared__ __align__(16) bf16 Bs[64 * 64];
  const bf16* A = U + (size_t)blockIdx.x * 128 * 1280;
  const bf16* B = WbT + (size_t)blockIdx.y * 64 * 1280;
  v4f acc[4][2];
#pragma unroll
  for (int a = 0; a < 4; ++a)
#pragma unroll
    for (int b2 = 0; b2 < 2; ++b2) acc[a][b2] = (v4f){0.f, 0.f, 0.f, 0.f};
  mfma_loop<2, 64>(A, B, 1280, 1280, 1280, As, Bs, acc);
  const int tid = threadIdx.x, wave = tid >> 6, lane = tid & 63;
  const int quad = lane >> 4, r16 = lane & 15;
  const int wm = (wave >> 1) * 64, wn = (wave & 1) * 32;
  const int i0 = blockIdx.x * 128 + wm + quad * 4;
  const int j0 = blockIdx.y * 64 + wn + r16;
#pragma unroll
  for (int mi = 0; mi < 4; ++mi)
#pragma unroll
    for (int r = 0; r < 4; ++r) {
      const int i = i0 + mi * 16 + r;
#pragma unroll
      for (int ni = 0; ni < 2; ++ni) {
        const int j = j0 + ni * 16;
        out[(size_t)i * 128 + j] = fmaxf(acc[mi][ni][r] + blin[j], 0.f);
      }
    }
}

extern "C" void kernel_launch(void* const* d_in, const int* in_sizes, int n_in,
                              void* d_out, int out_size, void* d_ws,
                              size_t ws_size, hipStream_t stream) {
  const float* x = (const float*)d_in[0];
  const float* Wk = (const float*)d_in[1];
  const float* Wlin = (const float*)d_in[2];
  const float* blin = (const float*)d_in[3];
  float* out = (float*)d_out;
  char* w = (char*)d_ws;
  // workspace layout (bytes):
  bf16* hpart = (bf16*)(w);               // 4*4*256*4096*2    = 33554432
  bf16* h1T = (bf16*)(w + 33554432);      // 4 * 256*4096 * 2  = 8388608
  bf16* xhT = (bf16*)(w + 41943040);      // 2 * 256*4096 * 2  = 4194304
  bf16* U = (bf16*)(w + 46137344);        // 8192*1280 * 2     = 20971520
  bf16* WbT = (bf16*)(w + 67108864);      // 128*1280 * 2      = 327680
  float* sqv = (float*)(w + 67436544);    // 8192 * 4          = 32768
  // total ~67.5 MB

  prep<<<dim3(4096, 2), 256, 0, stream>>>(x, U, sqv);
  transk<<<dim3(64, 4, 2), 256, 0, stream>>>(x, xhT);
  wbig<<<dim3(640), 256, 0, stream>>>(Wk, Wlin, WbT);
  // pass 1: h1 = spline(x x^T) @ x  (Vb == Vw == xhT[b]; batch stride 1 plane)
  fused_kh<<<dim3(64, 4, 2), 512, 0, stream>>>(U, sqv, xhT, xhT, 256 * 4096,
                                               hpart);
  reduceT<<<dim3(64, 4, 4), 256, 0, stream>>>(hpart, U, h1T, 256);
  // pass 2: h2 = spline(x x^T) @ h1 (Vb = h1T[2b], Vw = h1T[2b+1])
  fused_kh<<<dim3(64, 4, 2), 512, 0, stream>>>(U, sqv, h1T, h1T + 256 * 4096,
                                               2 * 256 * 4096, hpart);
  reduceT<<<dim3(64, 4, 4), 256, 0, stream>>>(hpart, U, nullptr, 512);
  gemm_proj<<<dim3(64, 2), 256, 0, stream>>>(U, WbT, blin, out);
}

// Round 8
// 248.538 us; speedup vs baseline: 2.3948x; 1.6602x over previous
//
#include <hip/hip_runtime.h>
#include <hip/hip_bf16.h>

typedef __hip_bfloat16 bf16;
typedef float v4f __attribute__((ext_vector_type(4)));
typedef short v8s __attribute__((ext_vector_type(8)));

typedef const __attribute__((address_space(1))) void gvoid;
typedef __attribute__((address_space(3))) void lvoid;

__device__ __forceinline__ void async16(const void* g, void* l) {
  __builtin_amdgcn_global_load_lds((gvoid*)g, (lvoid*)l, 16, 0, 0);
}

__device__ __forceinline__ unsigned short f2bf(float v) {
  __hip_bfloat16 h = __float2bfloat16(v);
  return *(unsigned short*)&h;
}
__device__ __forceinline__ float bflo(unsigned dw) {
  unsigned u = dw << 16;
  return *(float*)&u;
}
__device__ __forceinline__ float bfhi(unsigned dw) {
  unsigned u = dw & 0xffff0000u;
  return *(float*)&u;
}

// cardinal cubic B-spline on [0,4], 0 outside. Reference bspline(t) == b3(4t),
// wavelet(t) == b3(8t) - b3(8t-4). Clamp makes u>=4 exactly 0 (64-108+48-4).
__device__ __forceinline__ float b3(float u) {
  u = fminf(fmaxf(u, 0.f), 4.f);
  float t1 = fmaxf(u - 1.f, 0.f);
  float t2 = fmaxf(u - 2.f, 0.f);
  float t3 = fmaxf(u - 3.f, 0.f);
  float c0 = u * u * u;
  float c1 = t1 * t1 * t1;
  float c2 = t2 * t2 * t2;
  float c3 = t3 * t3 * t3;
  return (c0 - 4.f * c1 + 6.f * c2 - 4.f * c3) * (1.f / 6.f);
}

// m97-style NT GEMM mainloop: C[128 x NI*32] tile, BK elems per stage,
// bf16 MFMA 16x16x32. A: [*, lda] row-major (M rows), B: [*, ldb] row-major
// (N rows, i.e. B^T). As: 128*BK bf16, Bs: NI*32*BK bf16. 256 thr / 4 waves.
template <int NI, int BK>
__device__ __forceinline__ void mfma_loop(const bf16* __restrict__ A,
                                          const bf16* __restrict__ B, int lda,
                                          int ldb, int kLen, bf16* As, bf16* Bs,
                                          v4f acc[4][NI]) {
  const int tid = threadIdx.x;
  const int wave = tid >> 6;
  const int lane = tid & 63;
  const int quad = lane >> 4;
  const int r16 = lane & 15;
  const int wm = (wave >> 1) * 64;
  const int wn = (wave & 1) * (NI * 16);
  constexpr int CPR = BK / 8;          // 16B chunks per row
  constexpr int AQ = 128 * CPR / 256;  // async groups for A
  constexpr int BQ = NI * 32 * CPR / 256;
  char* AsC = (char*)As;
  char* BsC = (char*)Bs;
  for (int kk = 0; kk < kLen; kk += BK) {
#pragma unroll
    for (int q = 0; q < AQ; ++q) {
      const int ch = tid + 256 * q;
      const int r = ch / CPR, c = (ch % CPR) * 8;
      async16(A + (size_t)r * lda + kk + c, AsC + q * 4096 + wave * 1024);
    }
#pragma unroll
    for (int q = 0; q < BQ; ++q) {
      const int ch = tid + 256 * q;
      const int r = ch / CPR, c = (ch % CPR) * 8;
      async16(B + (size_t)r * ldb + kk + c, BsC + q * 4096 + wave * 1024);
    }
    __syncthreads();
#pragma unroll
    for (int ks = 0; ks < BK / 32; ++ks) {
      v8s af[4], bfr[NI];
#pragma unroll
      for (int mi = 0; mi < 4; ++mi)
        af[mi] =
            *(const v8s*)(As + (wm + mi * 16 + r16) * BK + ks * 32 + quad * 8);
#pragma unroll
      for (int ni = 0; ni < NI; ++ni)
        bfr[ni] =
            *(const v8s*)(Bs + (wn + ni * 16 + r16) * BK + ks * 32 + quad * 8);
#pragma unroll
      for (int mi = 0; mi < 4; ++mi)
#pragma unroll
        for (int ni = 0; ni < NI; ++ni)
          acc[mi][ni] = __builtin_amdgcn_mfma_f32_16x16x32_bf16(
              af[mi], bfr[ni], acc[mi][ni], 0, 0, 0);
    }
    __syncthreads();
  }
}

// per-row: sq-norm + bf16 cast of x into U[:, 0:256]
__global__ void prep(const float* __restrict__ x, bf16* __restrict__ U,
                     float* __restrict__ sq) {
  const int n = blockIdx.x, b = blockIdx.y, t = threadIdx.x;
  const size_t row = (size_t)b * 4096 + n;
  float v = x[row * 256 + t];
  U[row * 1280 + t] = __float2bfloat16(v);
  float s = v * v;
#pragma unroll
  for (int o = 32; o > 0; o >>= 1) s += __shfl_down(s, o, 64);
  __shared__ float ls[4];
  if ((t & 63) == 0) ls[t >> 6] = s;
  __syncthreads();
  if (t == 0) sq[row] = ls[0] + ls[1] + ls[2] + ls[3];
}

// fp32 [z][4096][256] -> bf16 [z][256][4096] (tiled transpose via LDS)
__global__ void transk(const float* __restrict__ src, bf16* __restrict__ dst) {
  __shared__ float tile[64][65];
  const int z = blockIdx.z;
  const float* s = src + (size_t)z * 4096 * 256;
  bf16* d = dst + (size_t)z * 256 * 4096;
  const int n0 = blockIdx.x * 64, d0 = blockIdx.y * 64;
  const int tx = threadIdx.x & 31, ty = threadIdx.x >> 5;
#pragma unroll
  for (int i = 0; i < 8; ++i) {
    const int r = ty + i * 8;
    const float2 v = *(const float2*)(s + (size_t)(n0 + r) * 256 + d0 + tx * 2);
    tile[r][tx * 2] = v.x;
    tile[r][tx * 2 + 1] = v.y;
  }
  __syncthreads();
#pragma unroll
  for (int i = 0; i < 8; ++i) {
    const int c = ty + i * 8;
    __hip_bfloat162 p;
    p.x = __float2bfloat16(tile[tx * 2][c]);
    p.y = __float2bfloat16(tile[tx * 2 + 1][c]);
    *(__hip_bfloat162*)(d + (size_t)(d0 + c) * 4096 + n0 + tx * 2) = p;
  }
}

// WbigT bf16 [128][1280]
__global__ void wbig(const float* __restrict__ Wk, const float* __restrict__ Wl,
                     bf16* __restrict__ WbT) {
  int idx = blockIdx.x * 256 + threadIdx.x;
  if (idx >= 128 * 1280) return;
  int j = idx / 1280, k = idx % 1280;
  int o = j & 63;
  float v = 0.f;
  if (k < 256)
    v = Wk[k * 64 + o] + Wl[k * 128 + j];
  else if (k < 512)
    v = (j < 64) ? Wk[16384 + (k - 256) * 64 + o] : 0.f;
  else if (k < 768)
    v = (j < 64) ? Wk[32768 + (k - 512) * 64 + o] : 0.f;
  else if (k < 1024)
    v = (j >= 64) ? Wk[16384 + (k - 768) * 64 + o] : 0.f;
  else
    v = (j >= 64) ? Wk[32768 + (k - 1024) * 64 + o] : 0.f;
  WbT[idx] = __float2bfloat16(v);
}

// S = x x^T tile + adjacency/spline epilogue -> bk, wk bf16 [4096][4096].
// Spline pair via 2048-entry LDS LUT over t=exp(-d2/512); paired-column
// dword stores via shfl_xor(1). LDS = 40K.
// bounds(256,2): R5-proven regalloc (VGPR 92, zero spill). bounds=3/4 make
// the compiler target the 128-reg config and spill (+16MB WRITE, R6/R7).
// Kernel is write-drain-bound ~2.8 TB/s; floor ~48us for 134MB.
__global__ __launch_bounds__(256, 2) void gemm_s(const bf16* __restrict__ U,
                                                 const float* __restrict__ sq,
                                                 bf16* __restrict__ kmat) {
  __shared__ __align__(16) bf16 As[128 * 64];
  __shared__ __align__(16) bf16 Bs[128 * 64];
  __shared__ unsigned lut[2048];
  const int tid = threadIdx.x;
  for (int i = tid; i < 2048; i += 256) {
    float t = (i + 0.5f) * (1.f / 2048.f);
    float bv = b3(4.f * t);
    float wv = b3(8.f * t) - b3(8.f * t - 4.f);
    lut[i] = (unsigned)f2bf(bv) | ((unsigned)f2bf(wv) << 16);
  }
  const int z = blockIdx.z;
  const bf16* A = U + (size_t)z * 4096 * 1280 + (size_t)blockIdx.x * 128 * 1280;
  const bf16* B = U + (size_t)z * 4096 * 1280 + (size_t)blockIdx.y * 128 * 1280;
  v4f acc[4][4];
#pragma unroll
  for (int a = 0; a < 4; ++a)
#pragma unroll
    for (int b2 = 0; b2 < 4; ++b2) acc[a][b2] = (v4f){0.f, 0.f, 0.f, 0.f};
  mfma_loop<4, 64>(A, B, 1280, 1280, 256, As, Bs, acc);
  const int wave = tid >> 6, lane = tid & 63;
  const int quad = lane >> 4, r16 = lane & 15;
  const int wm = (wave >> 1) * 64, wn = (wave & 1) * 64;
  const float* sqr = sq + (size_t)z * 4096;
  unsigned short* bk = (unsigned short*)(kmat + (size_t)(z * 2) * 4096 * 4096);
  unsigned short* wk = bk + (size_t)4096 * 4096;
  const int i0 = blockIdx.x * 128 + wm + quad * 4;
  const int j0 = blockIdx.y * 128 + wn + r16;
  const int par = lane & 1;  // 0: stores rows r=0,1 ; 1: rows r=2,3
  const int jc = j0 - par;   // even column of this lane's pair
  float sqj[4];
#pragma unroll
  for (int ni = 0; ni < 4; ++ni) sqj[ni] = sqr[j0 + ni * 16];
  const float c = -1.4426950408889634f / 512.f;  // -log2(e)/512
#pragma unroll
  for (int mi = 0; mi < 4; ++mi) {
#pragma unroll
    for (int ni = 0; ni < 4; ++ni) {
      unsigned pv[4];
#pragma unroll
      for (int r = 0; r < 4; ++r) {
        float s = acc[mi][ni][r];
        float d2 = fmaxf(sqr[i0 + mi * 16 + r] + sqj[ni] - 2.f * s, 0.f);
        float t = __builtin_amdgcn_exp2f(d2 * c);
        int idx = (int)fminf(t * 2048.f, 2047.f);
        pv[r] = lut[idx];
      }
      unsigned ov[4];
#pragma unroll
      for (int r = 0; r < 4; ++r) ov[r] = __shfl_xor((int)pv[r], 1, 64);
#pragma unroll
      for (int rr = 0; rr < 2; ++rr) {
        const int r = par * 2 + rr;
        const unsigned a = pv[r], b2 = ov[r];
        const unsigned lo = par ? b2 : a;  // left (even) column
        const unsigned hi = par ? a : b2;  // right (odd) column
        const unsigned bkd = (lo & 0xffffu) | (hi << 16);
        const unsigned wkd = (lo >> 16) | (hi & 0xffff0000u);
        const int i = i0 + mi * 16 + r;
        const size_t off = (size_t)i * 4096 + jc + ni * 16;
        *(unsigned*)(bk + off) = bkd;
        *(unsigned*)(wk + off) = wkd;
      }
    }
  }
}

// h-partial = K[:, split] @ H[split, :] : split-K x4, BK=64, 128x256 tile.
// R7 change vs baseline: output tile widened 128x128 -> 128x256 (512 thr,
// 8 waves in 2x4 grid), so each kmat A-panel (the dominant 268MB/pass of
// traffic) is streamed ONCE instead of twice (baseline blockIdx.y in {0,1}
// duplicated it). Same BK=64, same __syncthreads staging pattern, same
// fragment mapping and packed-pair epilogue as the proven baseline; per-wave
// acc[4][4] = the register shape gemm_s compiles cleanly (64-92 VGPR, no
// spill). LDS 48KB -> 2 blocks/CU possible; bounds (512,2) leaves the
// allocator free (forced caps caused the R5/R6 spills).
__global__ __launch_bounds__(512, 2) void gemm_h(const bf16* __restrict__ kmat,
                                                 const bf16* __restrict__ BtBase,
                                                 bf16* __restrict__ hpart,
                                                 int btShift) {
  __shared__ __align__(16) bf16 As[128 * 64];  // 16KB
  __shared__ __align__(16) bf16 Bs[256 * 64];  // 32KB
  const int bz = blockIdx.z;
  const int z = bz >> 2, split = bz & 3;
  const int kk0 = split * 1024;
  const bf16* A =
      kmat + (size_t)z * 4096 * 4096 + (size_t)blockIdx.x * 128 * 4096 + kk0;
  const bf16* B = BtBase + (size_t)(z >> btShift) * 256 * 4096 + kk0;
  const int tid = threadIdx.x, wave = tid >> 6, lane = tid & 63;
  const int quad = lane >> 4, r16 = lane & 15;
  const int wm = (wave >> 2) * 64;  // 2 row groups
  const int wn = (wave & 3) * 64;   // 4 col groups (full 256-wide B)
  char* AsC = (char*)As;
  char* BsC = (char*)Bs;
  v4f acc[4][4];
#pragma unroll
  for (int a = 0; a < 4; ++a)
#pragma unroll
    for (int b2 = 0; b2 < 4; ++b2) acc[a][b2] = (v4f){0.f, 0.f, 0.f, 0.f};
  for (int kk = 0; kk < 1024; kk += 64) {
#pragma unroll
    for (int q = 0; q < 2; ++q) {  // A: 128 rows x 8 chunks = 1024, 2/thread
      const int ch = tid + 512 * q;
      const int r = ch >> 3, c = (ch & 7) * 8;
      async16(A + (size_t)r * 4096 + kk + c, AsC + q * 8192 + wave * 1024);
    }
#pragma unroll
    for (int q = 0; q < 4; ++q) {  // B: 256 rows x 8 chunks = 2048, 4/thread
      const int ch = tid + 512 * q;
      const int r = ch >> 3, c = (ch & 7) * 8;
      async16(B + (size_t)r * 4096 + kk + c, BsC + q * 8192 + wave * 1024);
    }
    __syncthreads();
#pragma unroll
    for (int ks = 0; ks < 2; ++ks) {
      v8s af[4], bfr[4];
#pragma unroll
      for (int mi = 0; mi < 4; ++mi)
        af[mi] =
            *(const v8s*)(As + (wm + mi * 16 + r16) * 64 + ks * 32 + quad * 8);
#pragma unroll
      for (int ni = 0; ni < 4; ++ni)
        bfr[ni] =
            *(const v8s*)(Bs + (wn + ni * 16 + r16) * 64 + ks * 32 + quad * 8);
#pragma unroll
      for (int mi = 0; mi < 4; ++mi)
#pragma unroll
        for (int ni = 0; ni < 4; ++ni)
          acc[mi][ni] = __builtin_amdgcn_mfma_f32_16x16x32_bf16(
              af[mi], bfr[ni], acc[mi][ni], 0, 0, 0);
    }
    __syncthreads();
  }
  // epilogue: bf16 partials (packed pairs, dword stores), H[i][d] layout
  bf16* H = hpart + ((size_t)split * 4 + z) * 4096 * 256;
  const int i0 = blockIdx.x * 128 + wm + quad * 4;
  const int j0 = wn + r16;
  const int par = lane & 1;
  const int jc = j0 - par;
#pragma unroll
  for (int mi = 0; mi < 4; ++mi) {
#pragma unroll
    for (int ni = 0; ni < 4; ++ni) {
      unsigned pv[4];
#pragma unroll
      for (int r = 0; r < 4; ++r) pv[r] = (unsigned)f2bf(acc[mi][ni][r]);
      unsigned ov[4];
#pragma unroll
      for (int r = 0; r < 4; ++r) ov[r] = __shfl_xor((int)pv[r], 1, 64);
#pragma unroll
      for (int rr = 0; rr < 2; ++rr) {
        const int r = par * 2 + rr;
        const unsigned a = pv[r], b2 = ov[r];
        const unsigned lo = par ? b2 : a;
        const unsigned hi = par ? a : b2;
        const int i = i0 + mi * 16 + r;
        *(unsigned*)(H + (size_t)i * 256 + jc + ni * 16) = lo | (hi << 16);
      }
    }
  }
}

// sum the four bf16 split-K partials; write bf16 slice into U[:, uoff..] and
// (pass 1 only) transposed bf16 into hT [z][256][4096].
__global__ void reduceT(const bf16* __restrict__ hpart, bf16* __restrict__ U,
                        bf16* __restrict__ hT, int uoffBase) {
  __shared__ float tile[64][65];
  const int z = blockIdx.z;
  const int b = z >> 1, kern = z & 1;
  const int uoff = uoffBase + kern * 512;
  const int n0 = blockIdx.x * 64, d0 = blockIdx.y * 64;
  const int tx = threadIdx.x & 31, ty = threadIdx.x >> 5;
  const size_t sstride = (size_t)4 * 4096 * 256;
  const bf16* s0 = hpart + (size_t)z * 4096 * 256;
#pragma unroll
  for (int i = 0; i < 8; ++i) {
    const int r = ty + i * 8;
    const size_t off = (size_t)(n0 + r) * 256 + d0 + tx * 2;
    float vx = 0.f, vy = 0.f;
#pragma unroll
    for (int k = 0; k < 4; ++k) {
      const unsigned dw = *(const unsigned*)(s0 + k * sstride + off);
      vx += bflo(dw);
      vy += bfhi(dw);
    }
    tile[r][tx * 2] = vx;
    tile[r][tx * 2 + 1] = vy;
    __hip_bfloat162 p;
    p.x = __float2bfloat16(vx);
    p.y = __float2bfloat16(vy);
    *(__hip_bfloat162*)(U + (size_t)(b * 4096 + n0 + r) * 1280 + uoff + d0 +
                        tx * 2) = p;
  }
  if (hT) {
    __syncthreads();
#pragma unroll
    for (int i = 0; i < 8; ++i) {
      const int c = ty + i * 8;
      __hip_bfloat162 p;
      p.x = __float2bfloat16(tile[tx * 2][c]);
      p.y = __float2bfloat16(tile[tx * 2 + 1][c]);
      *(__hip_bfloat162*)(hT + (size_t)z * 256 * 4096 + (size_t)(d0 + c) * 4096 +
                          n0 + tx * 2) = p;
    }
  }
}

// out = relu(U @ Wbig + b_lin), M=8192, K=1280, N=128
__global__ __launch_bounds__(256, 4) void gemm_proj(
    const bf16* __restrict__ U, const bf16* __restrict__ WbT,
    const float* __restrict__ blin, float* __restrict__ out) {
  __shared__ __align__(16) bf16 As[128 * 64];
  __shared__ __align__(16) bf16 Bs[64 * 64];
  const bf16* A = U + (size_t)blockIdx.x * 128 * 1280;
  const bf16* B = WbT + (size_t)blockIdx.y * 64 * 1280;
  v4f acc[4][2];
#pragma unroll
  for (int a = 0; a < 4; ++a)
#pragma unroll
    for (int b2 = 0; b2 < 2; ++b2) acc[a][b2] = (v4f){0.f, 0.f, 0.f, 0.f};
  mfma_loop<2, 64>(A, B, 1280, 1280, 1280, As, Bs, acc);
  const int tid = threadIdx.x, wave = tid >> 6, lane = tid & 63;
  const int quad = lane >> 4, r16 = lane & 15;
  const int wm = (wave >> 1) * 64, wn = (wave & 1) * 32;
  const int i0 = blockIdx.x * 128 + wm + quad * 4;
  const int j0 = blockIdx.y * 64 + wn + r16;
#pragma unroll
  for (int mi = 0; mi < 4; ++mi)
#pragma unroll
    for (int r = 0; r < 4; ++r) {
      const int i = i0 + mi * 16 + r;
#pragma unroll
      for (int ni = 0; ni < 2; ++ni) {
        const int j = j0 + ni * 16;
        out[(size_t)i * 128 + j] = fmaxf(acc[mi][ni][r] + blin[j], 0.f);
      }
    }
}

extern "C" void kernel_launch(void* const* d_in, const int* in_sizes, int n_in,
                              void* d_out, int out_size, void* d_ws,
                              size_t ws_size, hipStream_t stream) {
  const float* x = (const float*)d_in[0];
  const float* Wk = (const float*)d_in[1];
  const float* Wlin = (const float*)d_in[2];
  const float* blin = (const float*)d_in[3];
  float* out = (float*)d_out;
  char* w = (char*)d_ws;
  // workspace layout (bytes):
  bf16* kmat = (bf16*)(w);                // 4 * 4096*4096 * 2  = 134217728
  bf16* hpart = (bf16*)(w + 134217728);   // 4 * 4*4096*256*2   = 33554432
  bf16* h1T = (bf16*)(w + 201326592);     // 4 * 256*4096 * 2   = 8388608
  bf16* xhT = (bf16*)(w + 209715200);     // 2 * 256*4096 * 2   = 4194304
  bf16* U = (bf16*)(w + 213909504);       // 8192*1280 * 2      = 20971520
  bf16* WbT = (bf16*)(w + 234881024);     // 128*1280 * 2       = 327680
  float* sqv = (float*)(w + 235208704);   // 8192 * 4           = 32768
  // total ~235.2 MB

  prep<<<dim3(4096, 2), 256, 0, stream>>>(x, U, sqv);
  transk<<<dim3(64, 4, 2), 256, 0, stream>>>(x, xhT);
  wbig<<<dim3(640), 256, 0, stream>>>(Wk, Wlin, WbT);
  gemm_s<<<dim3(32, 32, 2), 256, 0, stream>>>(U, sqv, kmat);
  // pass 1: h1 = K @ x
  gemm_h<<<dim3(32, 1, 16), 512, 0, stream>>>(kmat, xhT, hpart, 1);
  reduceT<<<dim3(64, 4, 4), 256, 0, stream>>>(hpart, U, h1T, 256);
  // pass 2: h2 = K @ h1
  gemm_h<<<dim3(32, 1, 16), 512, 0, stream>>>(kmat, h1T, hpart, 0);
  reduceT<<<dim3(64, 4, 4), 256, 0, stream>>>(hpart, U, nullptr, 512);
  gemm_proj<<<dim3(64, 2), 256, 0, stream>>>(U, WbT, blin, out);
}